// Round 2
// baseline (142.985 us; speedup 1.0000x reference)
//
#include <hip/hip_runtime.h>
#include <hip/hip_bf16.h>

// Problem constants (fixed by reference setup_inputs)
constexpr int NWIN = 49;     // 7x7 windows
constexpr int QLD  = 52;     // padded row length for 49-length rows (13 float4)

// workspace layout (float offsets)
constexpr int OFF_WS   = 0;            // [8][64][52]      = 26624 (bt, s, win)
constexpr int OFF_Q    = 26624;        // [2][128][4][52]  = 53248 (b, d, t, n)
constexpr int OFF_QSP  = 79872;        // [2][4][128][64]  = 65536 (b, t, d, s)
constexpr int OFF_A12  = 145408;       // [2][3][64][64]  (only t=0 written)
constexpr int OFF_A12T = 169984;       // (only t=1,2 written)
constexpr int OFF_A21  = 194560;       // (only t=1,2 written)
constexpr int OFF_A21T = 219136;       // (only t=0 written)
constexpr int OFF_P    = 243712;       // [2][4096]  P    = A12_0 @ A12_1
constexpr int OFF_R1T  = 251904;       // [2][4096]  R1^T = A21_0^T @ A21_1^T
constexpr int OFF_L    = 260096;       // [2][4096]  L    = P @ A12_2
constexpr int OFF_RT   = 268288;       // [2][4096]  R^T  = R1T @ A21_2^T
constexpr int OFF_BAR  = 276480;       // 4 ints (barrier counters)

// ---------------------------------------------------------------------------
// K1: fused front end — blocks [0,392): scatter; blocks [392,490): q head.
// Block 0 additionally zeroes the device-barrier counters + loss accumulator
// (stream order guarantees visibility before k_tail2 starts).
__global__ void __launch_bounds__(256, 1)
k_front(const int* __restrict__ mask, const float* __restrict__ feats,
        const float* __restrict__ Wh, float* __restrict__ ws, float* __restrict__ q,
        float* __restrict__ out, int* __restrict__ bar) {
    if (blockIdx.x < 392) {
        if (blockIdx.x == 0) {
            if (threadIdx.x < 4) bar[threadIdx.x] = 0;
            if (threadIdx.x == 4) out[0] = 0.f;
        }
        int win = blockIdx.x % NWIN;
        int bt  = blockIdx.x / NWIN;
        int wy = win / 7, wx = win % 7;
        __shared__ float loc[64];
        if (threadIdx.x < 64) loc[threadIdx.x] = 0.f;
        __syncthreads();
        const int* base = mask + bt * 65536 + (wy * 32) * 256 + wx * 32;
        #pragma unroll
        for (int it = 0; it < 16; ++it) {
            int idx = it * 256 + (int)threadIdx.x;
            int r = idx >> 6, c = idx & 63;
            int s = base[r * 256 + c];
            int y = wy * 32 + r, x = wx * 32 + c;
            float w = 1.f;
            if (y >= 32 && y < 224) w *= 0.5f;   // row coverage = 2
            if (x >= 32 && x < 224) w *= 0.5f;   // col coverage = 2
            atomicAdd(&loc[s], w);
        }
        __syncthreads();
        if (threadIdx.x < 64) {
            ws[(bt * 64 + (int)threadIdx.x) * QLD + win] = loc[threadIdx.x];
        } else if (win == 0) {
            int s = threadIdx.x & 63;
            int col = 49 + (int)(threadIdx.x >> 6) - 1;   // 49,50,51
            ws[(bt * 64 + s) * QLD + col] = 0.f;
        }
    } else {
        // q[b][d][t][n] = normalize_d(feats[b,n,:,t] @ Wh[:,d])
        // feats access is wave-uniform (c is uniform) -> 16B broadcast loads
        // straight from L1/L2; no LDS staging (frees the DS pipe entirely).
        int bid = blockIdx.x - 392;
        int n = bid % NWIN, b = bid / NWIN;
        __shared__ float4 psum4[256];
        __shared__ float4 red4[2];
        const float4* fp4 = (const float4*)(feats + (size_t)(b * NWIN + n) * 2048);

        int d = threadIdx.x & 127, ch = threadIdx.x >> 7;
        float a0 = 0.f, a1 = 0.f, a2 = 0.f, a3 = 0.f;
        const float* wp = Wh + d;
        int c0 = ch * 256;
        #pragma unroll 8
        for (int c = c0; c < c0 + 256; ++c) {
            float w = wp[c * 128];
            float4 fv = fp4[c];
            a0 += fv.x * w; a1 += fv.y * w; a2 += fv.z * w; a3 += fv.w * w;
        }
        psum4[threadIdx.x] = make_float4(a0, a1, a2, a3);
        __syncthreads();

        float4 A;
        if (threadIdx.x < 128) {
            float4 p0 = psum4[threadIdx.x], p1 = psum4[128 + threadIdx.x];
            A = make_float4(p0.x + p1.x, p0.y + p1.y, p0.z + p1.z, p0.w + p1.w);
            float sx = A.x * A.x, sy = A.y * A.y, sz = A.z * A.z, sw = A.w * A.w;
            for (int off = 32; off; off >>= 1) {
                sx += __shfl_down(sx, off); sy += __shfl_down(sy, off);
                sz += __shfl_down(sz, off); sw += __shfl_down(sw, off);
            }
            if ((threadIdx.x & 63) == 0) red4[threadIdx.x >> 6] = make_float4(sx, sy, sz, sw);
        }
        __syncthreads();
        if (threadIdx.x < 128) {
            float4 r0 = red4[0], r1 = red4[1];
            float ix = 1.f / fmaxf(sqrtf(r0.x + r1.x), 1e-12f);
            float iy = 1.f / fmaxf(sqrtf(r0.y + r1.y), 1e-12f);
            float iz = 1.f / fmaxf(sqrtf(r0.z + r1.z), 1e-12f);
            float iw = 1.f / fmaxf(sqrtf(r0.w + r1.w), 1e-12f);
            float* qb = q + (size_t)(b * 128 + d) * 4 * QLD + n;
            qb[0 * QLD] = A.x * ix;
            qb[1 * QLD] = A.y * iy;
            qb[2 * QLD] = A.z * iz;
            qb[3 * QLD] = A.w * iw;
        }
    }
}

// ---------------------------------------------------------------------------
// Shared helpers for the fused tail.
// XOR-4-swizzled LDS matrix layout: element (r,k) of a 64x64 matrix lives at
// M[r*64 + (((k>>2)^(r&15))<<2)+(k&3)].

__device__ __forceinline__ void dump_mat(float* M, const float4* v) {
    #pragma unroll
    for (int it = 0; it < 4; ++it) {
        int idx = it * 256 + (int)threadIdx.x;
        int r = idx >> 4, c4 = (idx & 15) << 2;
        *(float4*)&M[r * 64 + (c4 ^ ((r & 15) << 2))] = v[it];
    }
}

// stage two 64x64 row-major global matrices into swizzled LDS (coalesced)
__device__ __forceinline__ void stage2(float* Ma, float* Mb,
                                       const float* __restrict__ Ga,
                                       const float* __restrict__ Gb) {
    const float4* ga = (const float4*)Ga;
    const float4* gb = (const float4*)Gb;
    float4 va[4], vb[4];
    #pragma unroll
    for (int it = 0; it < 4; ++it) {
        int idx = it * 256 + (int)threadIdx.x;
        va[it] = ga[idx];
        vb[it] = gb[idx];
    }
    dump_mat(Ma, va);
    dump_mat(Mb, vb);
}

// full-block mm (k=64, 4x4 tiles), swizzled LDS operands. C = Ra @ Rb^T.
__device__ __forceinline__ void mm256_sw(float* acc, const float* Ra, const float* Rb) {
    int tid = threadIdx.x;
    int nl = tid >> 4, ml = tid & 15;
    int sxa = nl << 2, sxb = ml << 2;
    #pragma unroll
    for (int i = 0; i < 16; ++i) acc[i] = 0.f;
    #pragma unroll 4
    for (int k0 = 0; k0 < 64; k0 += 4) {
        float4 av[4], bv[4];
        #pragma unroll
        for (int i = 0; i < 4; ++i)
            av[i] = *(const float4*)&Ra[(nl + 16 * i) * 64 + (k0 ^ sxa)];
        #pragma unroll
        for (int j = 0; j < 4; ++j)
            bv[j] = *(const float4*)&Rb[(ml + 16 * j) * 64 + (k0 ^ sxb)];
        #pragma unroll
        for (int i = 0; i < 4; ++i)
            #pragma unroll
            for (int j = 0; j < 4; ++j)
                acc[i * 4 + j] += av[i].x * bv[j].x + av[i].y * bv[j].y
                                + av[i].z * bv[j].z + av[i].w * bv[j].w;
    }
}

// store 64x64 result row-major to global (4 x 64B segments per store instr)
__device__ __forceinline__ void store_mat(float* __restrict__ G, const float* acc) {
    int nl = threadIdx.x >> 4, ml = threadIdx.x & 15;
    #pragma unroll
    for (int i = 0; i < 4; ++i)
        #pragma unroll
        for (int j = 0; j < 4; ++j)
            G[(nl + 16 * i) * 64 + ml + 16 * j] = acc[i * 4 + j];
}

// store aa + fused loss from registers (proven epilogue)
__device__ __forceinline__ void store_loss(const float* acc, float* __restrict__ aa,
                                           float* __restrict__ out, float* red) {
    int tid = threadIdx.x;
    int nl = tid >> 4, ml = tid & 15;
    #pragma unroll
    for (int i = 0; i < 4; ++i)
        #pragma unroll
        for (int j = 0; j < 4; ++j)
            aa[(nl + 16 * i) * 64 + (ml + 16 * j)] = acc[i * 4 + j];
    int l = tid & 63;
    float part = 0.f;
    #pragma unroll
    for (int i = 0; i < 4; ++i) {
        float rsum = acc[i * 4 + 0] + acc[i * 4 + 1] + acc[i * 4 + 2] + acc[i * 4 + 3];
        rsum += __shfl_down(rsum, 8, 16);
        rsum += __shfl_down(rsum, 4, 16);
        rsum += __shfl_down(rsum, 2, 16);
        rsum += __shfl_down(rsum, 1, 16);
        float dv = __shfl(acc[5 * i], (l & 48) | nl, 64);
        if ((l & 15) == 0) part += logf(rsum + 6.4e-19f) - logf(dv + 1e-20f);
    }
    for (int off = 32; off; off >>= 1) part += __shfl_down(part, off);
    if (l == 0) red[tid >> 6] = part;
    __syncthreads();
    if (tid == 0) atomicAdd(out, (red[0] + red[1] + red[2] + red[3]) * (1.f / 128.f));
}

// device-scope spin barrier; single-use counter (pre-zeroed by k_front).
__device__ __forceinline__ void gbar(int* cnt, int target) {
    __threadfence();
    __syncthreads();
    if (threadIdx.x == 0) {
        __hip_atomic_fetch_add(cnt, 1, __ATOMIC_ACQ_REL, __HIP_MEMORY_SCOPE_AGENT);
        while (__hip_atomic_load(cnt, __ATOMIC_ACQUIRE, __HIP_MEMORY_SCOPE_AGENT) < target)
            __builtin_amdgcn_s_sleep(2);
    }
    __syncthreads();
    __threadfence();
}

// ---------------------------------------------------------------------------
// K2: fused qsp + As/zero_softmax + chain. grid = 256, block = 256.
// phase Q (256 blk): qsp[b][t][d][s]  (one thread per output, as before)
//   bar0 (target 256): blocks >= 6 arrive and exit; blocks 0..5 wait.
// phase A (6 blk): As/zero_softmax jobs (b,t); write only consumed layouts.
// phase B (4 blk): P_b = A12_0@A12_1 ; R1T_b = A21_0^T@A21_1^T
// phase C (6 blk): aa1_b = P@R1 (+loss) ; L_b = P@A12_2 ; RT_b = R1T@A21_2^T
// phase D (2 blk): aa2_b = L@R (+loss)
// Co-residency: 64 KB LDS -> 2 blocks/CU capacity; launch_bounds(256,2)
// caps VGPR<=256 so 256 blocks are always simultaneously resident.
__global__ void __launch_bounds__(256, 2)
k_tail2(const float* __restrict__ q, const float* __restrict__ wsg,
        float* __restrict__ qsp,
        float* __restrict__ a12, float* __restrict__ a12T,
        float* __restrict__ a21, float* __restrict__ a21T,
        float* __restrict__ wsP, float* __restrict__ wsR1T,
        float* __restrict__ wsL, float* __restrict__ wsRT,
        float* __restrict__ out, int* __restrict__ bar) {
    __shared__ float SM[16384];           // 64 KB, aliased per phase
    const int tid = threadIdx.x;
    const int blk = blockIdx.x;

    // ---------------- phase Q: qsp (proven k_qsp body) ---------------------
    {
        int gid = blk * 256 + tid;          // ((b*4+t)*128+d)*64+s
        int s = gid & 63;
        int d = (gid >> 6) & 127;
        int t = (gid >> 13) & 3;
        int b = gid >> 15;
        const float4* qrow = (const float4*)(q + (size_t)((b * 128 + d) * 4 + t) * QLD);
        const float4* wrow = (const float4*)(wsg + (size_t)((b * 4 + t) * 64 + s) * QLD);
        float acc = 0.f, den = 0.f;
        #pragma unroll
        for (int i = 0; i < 13; ++i) {
            float4 w = wrow[i];
            float4 qv = qrow[i];
            den += w.x + w.y + w.z + w.w;
            acc += qv.x * w.x + qv.y * w.y + qv.z * w.z + qv.w * w.w;
        }
        qsp[gid] = acc / (den + 1e-20f);
    }
    // bar0: publish qsp; non-tail blocks exit after arrival.
    __threadfence();
    __syncthreads();
    if (blk >= 6) {
        if (tid == 0)
            __hip_atomic_fetch_add(bar + 0, 1, __ATOMIC_ACQ_REL, __HIP_MEMORY_SCOPE_AGENT);
        return;
    }
    if (tid == 0) {
        __hip_atomic_fetch_add(bar + 0, 1, __ATOMIC_ACQ_REL, __HIP_MEMORY_SCOPE_AGENT);
        while (__hip_atomic_load(bar + 0, __ATOMIC_ACQUIRE, __HIP_MEMORY_SCOPE_AGENT) < 256)
            __builtin_amdgcn_s_sleep(2);
    }
    __syncthreads();
    __threadfence();

    // ---------------- phase A: As + zero_softmax (proven body) -------------
    {
        int t = blk % 3, b = blk / 3;
        float4* qaT4 = (float4*)SM;              // [64][32] swizzled (s-major)
        float4* qbT4 = (float4*)SM + 2048;
        {
            const float4* gA = (const float4*)(qsp + (size_t)(b * 4 + t) * 8192);
            const float4* gB = (const float4*)(qsp + (size_t)(b * 4 + t + 1) * 8192);
            float* qaF = (float*)qaT4;
            float* qbF = (float*)qbT4;
            #pragma unroll
            for (int it = 0; it < 8; ++it) {
                int idx = it * 256 + tid;           // float4 index over [d][s/4]
                int d = idx >> 4, s0 = (idx & 15) << 2;
                float4 va = gA[idx];
                float4 vb = gB[idx];
                int g = d >> 2, c = d & 3;
                #pragma unroll
                for (int u = 0; u < 4; ++u) {
                    int s = s0 + u;
                    int w = (s * 32 + (g ^ (s & 31))) * 4 + c;
                    float fa = (u == 0) ? va.x : (u == 1) ? va.y : (u == 2) ? va.z : va.w;
                    float fb = (u == 0) ? vb.x : (u == 1) ? vb.y : (u == 2) ? vb.z : vb.w;
                    qaF[w] = fa;
                    qbF[w] = fb;
                }
            }
        }
        __syncthreads();

        const int nl = tid >> 4, ml = tid & 15;
        float acc[16];
        #pragma unroll
        for (int i = 0; i < 16; ++i) acc[i] = 0.f;
        #pragma unroll 8
        for (int k4 = 0; k4 < 32; ++k4) {
            float4 av[4], bv[4];
            #pragma unroll
            for (int i = 0; i < 4; ++i) { int n = nl + 16 * i; av[i] = qaT4[n * 32 + (k4 ^ (n & 31))]; }
            #pragma unroll
            for (int j = 0; j < 4; ++j) { int m = ml + 16 * j; bv[j] = qbT4[m * 32 + (k4 ^ (m & 31))]; }
            #pragma unroll
            for (int i = 0; i < 4; ++i)
                #pragma unroll
                for (int j = 0; j < 4; ++j)
                    acc[i * 4 + j] += av[i].x * bv[j].x + av[i].y * bv[j].y
                                    + av[i].z * bv[j].z + av[i].w * bv[j].w;
        }
        __syncthreads();

        float* eb = (float*)qaT4;          // [64][65]
        float* rs = (float*)qbT4;          // [64]
        float* cs = rs + 64;               // [64]
        #pragma unroll
        for (int i = 0; i < 4; ++i)
            #pragma unroll
            for (int j = 0; j < 4; ++j) {
                int n = nl + 16 * i, m = ml + 16 * j;
                float x = acc[i * 4 + j] * (1.f / 0.07f);
                float e = expf(x) - 1.f;
                eb[n * 65 + m] = e * e;
            }
        __syncthreads();
        if (tid < 128) {
            int r = tid & 63; bool isrow = tid < 64;
            float a = 0.f;
            #pragma unroll
            for (int k = 0; k < 64; ++k) a += isrow ? eb[r * 65 + k] : eb[k * 65 + r];
            (isrow ? rs : cs)[r] = a + 1e-5f;
        }
        __syncthreads();
        // Only the orientations the chain consumes:
        //   t==0: A12_0 rows (Ra of P), A21_0^T rows (Ra of R1T)
        //   t>0 : A12_t^T rows (Rb), A21_t rows (Rb)
        float* p12  = a12  + (b * 3 + t) * 4096;
        float* p12T = a12T + (b * 3 + t) * 4096;
        float* p21  = a21  + (b * 3 + t) * 4096;
        float* p21T = a21T + (b * 3 + t) * 4096;
        #pragma unroll
        for (int i = 0; i < 4; ++i)
            #pragma unroll
            for (int j = 0; j < 4; ++j) {
                int n = nl + 16 * i, m = ml + 16 * j;
                float v   = eb[n * 65 + m];
                float v12 = v / rs[n];           // A12[n][m]
                float v21 = v / cs[m];           // A21[m][n]
                if (t == 0) {
                    p12 [n * 64 + m] = v12;      // A12_0 rows
                    p21T[n * 64 + m] = v21;      // A21_0^T rows
                } else {
                    p12T[m * 64 + n] = v12;      // A12_t^T rows
                    p21 [m * 64 + n] = v21;      // A21_t rows
                }
            }
    }
    gbar(bar + 1, 6);

    // ---------------- phase B: r1 (4 independent 64^3 mms) -----------------
    if (blk < 4) {
        int b = blk >> 1, which = blk & 1;
        float* Ma = SM;
        float* Mb = SM + 4096;
        if (which == 0) stage2(Ma, Mb, a12  + (b * 3 + 0) * 4096, a12T + (b * 3 + 1) * 4096);
        else            stage2(Ma, Mb, a21T + (b * 3 + 0) * 4096, a21  + (b * 3 + 1) * 4096);
        __syncthreads();
        float acc[16];
        mm256_sw(acc, Ma, Mb);                 // P = A12_0@A12_1 | R1T = A21_0^T@A21_1^T
        store_mat((which == 0 ? wsP : wsR1T) + b * 4096, acc);
    }
    gbar(bar + 2, 6);

    // ---------------- phase C: aa1 (+loss) and r2 (6 mms) ------------------
    {
        float* Ma = SM;
        float* Mb = SM + 4096;
        float* red = SM + 8192;
        if (blk < 2) {                          // aa1_b = P @ R1
            int b = blk;
            stage2(Ma, Mb, wsP + b * 4096, wsR1T + b * 4096);
            __syncthreads();
            float acc[16];
            mm256_sw(acc, Ma, Mb);
            store_loss(acc, out + 1 + b * 4096, out, red);
        } else if (blk < 4) {                   // L_b = P @ A12_2
            int b = blk - 2;
            stage2(Ma, Mb, wsP + b * 4096, a12T + (b * 3 + 2) * 4096);
            __syncthreads();
            float acc[16];
            mm256_sw(acc, Ma, Mb);
            store_mat(wsL + b * 4096, acc);
        } else {                                // RT_b = R1T @ A21_2^T = (A21_2@R1)^T
            int b = blk - 4;
            stage2(Ma, Mb, wsR1T + b * 4096, a21 + (b * 3 + 2) * 4096);
            __syncthreads();
            float acc[16];
            mm256_sw(acc, Ma, Mb);
            store_mat(wsRT + b * 4096, acc);
        }
    }
    gbar(bar + 3, 6);

    // ---------------- phase D: aa2 (+loss), 2 mms --------------------------
    if (blk < 2) {
        int b = blk;
        float* Ma = SM;
        float* Mb = SM + 4096;
        float* red = SM + 8192;
        stage2(Ma, Mb, wsL + b * 4096, wsRT + b * 4096);
        __syncthreads();
        float acc[16];
        mm256_sw(acc, Ma, Mb);                  // aa2 = L @ R
        store_loss(acc, out + 1 + (2 + b) * 4096, out, red);
    }
}

// ---------------------------------------------------------------------------
extern "C" void kernel_launch(void* const* d_in, const int* in_sizes, int n_in,
                              void* d_out, int out_size, void* d_ws, size_t ws_size,
                              hipStream_t stream) {
    const float* feats = (const float*)d_in[0];
    const float* Wh    = (const float*)d_in[1];
    const int*   mask  = (const int*)d_in[2];
    float* out = (float*)d_out;
    float* ws  = (float*)d_ws;

    float* ws_sums = ws + OFF_WS;
    float* q       = ws + OFF_Q;
    float* qsp     = ws + OFF_QSP;
    float* a12     = ws + OFF_A12;
    float* a12T    = ws + OFF_A12T;
    float* a21     = ws + OFF_A21;
    float* a21T    = ws + OFF_A21T;
    float* wsP     = ws + OFF_P;
    float* wsR1T   = ws + OFF_R1T;
    float* wsL     = ws + OFF_L;
    float* wsRT    = ws + OFF_RT;
    int*   bar     = (int*)(ws + OFF_BAR);

    k_front<<<392 + 2 * NWIN, 256, 0, stream>>>(mask, feats, Wh, ws_sums, q, out, bar);
    k_tail2<<<256, 256, 0, stream>>>(q, ws_sums, qsp, a12, a12T, a21, a21T,
                                     wsP, wsR1T, wsL, wsRT, out, bar);
}

// Round 3
// 120.322 us; speedup vs baseline: 1.1884x; 1.1884x over previous
//
#include <hip/hip_runtime.h>
#include <hip/hip_bf16.h>

// Problem constants (fixed by reference setup_inputs)
constexpr int NWIN = 49;     // 7x7 windows
constexpr int QLD  = 52;     // padded row length for 49-length rows (13 float4)

// workspace layout (float offsets)
constexpr int OFF_WS   = 0;            // [8][64][52]      = 26624 (bt, s, win)
constexpr int OFF_Q    = 26624;        // [2][128][4][52]  = 53248 (b, d, t, n)
constexpr int OFF_QSP  = 79872;        // [2][4][128][64]  = 65536 (b, t, d, s)
constexpr int OFF_A12  = 145408;       // [2][3][64][64]  (only t=0 written)
constexpr int OFF_A12T = 169984;       // (only t=1,2 written)
constexpr int OFF_A21  = 194560;       // (only t=1,2 written)
constexpr int OFF_A21T = 219136;       // (only t=0 written)
constexpr int OFF_P    = 243712;       // [2][4096]  P    = A12_0 @ A12_1
constexpr int OFF_R1T  = 251904;       // [2][4096]  R1^T = A21_0^T @ A21_1^T
constexpr int OFF_L    = 260096;       // [2][4096]  L    = P @ A12_2
constexpr int OFF_RT   = 268288;       // [2][4096]  R^T  = R1T @ A21_2^T
constexpr int OFF_BAR  = 276480;       // 4 ints (barrier counters)

// ---------------------------------------------------------------------------
// K1: fused front end — blocks [0,392): scatter; blocks [392,490): q head.
__global__ void __launch_bounds__(256, 1)
k_front(const int* __restrict__ mask, const float* __restrict__ feats,
        const float* __restrict__ Wh, float* __restrict__ ws, float* __restrict__ q) {
    if (blockIdx.x < 392) {
        int win = blockIdx.x % NWIN;
        int bt  = blockIdx.x / NWIN;
        int wy = win / 7, wx = win % 7;
        __shared__ float loc[64];
        if (threadIdx.x < 64) loc[threadIdx.x] = 0.f;
        __syncthreads();
        const int* base = mask + bt * 65536 + (wy * 32) * 256 + wx * 32;
        #pragma unroll
        for (int it = 0; it < 16; ++it) {
            int idx = it * 256 + (int)threadIdx.x;
            int r = idx >> 6, c = idx & 63;
            int s = base[r * 256 + c];
            int y = wy * 32 + r, x = wx * 32 + c;
            float w = 1.f;
            if (y >= 32 && y < 224) w *= 0.5f;   // row coverage = 2
            if (x >= 32 && x < 224) w *= 0.5f;   // col coverage = 2
            atomicAdd(&loc[s], w);
        }
        __syncthreads();
        if (threadIdx.x < 64) {
            ws[(bt * 64 + (int)threadIdx.x) * QLD + win] = loc[threadIdx.x];
        } else if (win == 0) {
            int s = threadIdx.x & 63;
            int col = 49 + (int)(threadIdx.x >> 6) - 1;   // 49,50,51
            ws[(bt * 64 + s) * QLD + col] = 0.f;
        }
    } else {
        // q[b][d][t][n] = normalize_d(feats[b,n,:,t] @ Wh[:,d])
        // feats access is wave-uniform (c is uniform) -> 16B broadcast loads
        // straight from L1/L2; no LDS staging (frees the DS pipe entirely).
        int bid = blockIdx.x - 392;
        int n = bid % NWIN, b = bid / NWIN;
        __shared__ float4 psum4[256];
        __shared__ float4 red4[2];
        const float4* fp4 = (const float4*)(feats + (size_t)(b * NWIN + n) * 2048);

        int d = threadIdx.x & 127, ch = threadIdx.x >> 7;
        float a0 = 0.f, a1 = 0.f, a2 = 0.f, a3 = 0.f;
        const float* wp = Wh + d;
        int c0 = ch * 256;
        #pragma unroll 8
        for (int c = c0; c < c0 + 256; ++c) {
            float w = wp[c * 128];
            float4 fv = fp4[c];
            a0 += fv.x * w; a1 += fv.y * w; a2 += fv.z * w; a3 += fv.w * w;
        }
        psum4[threadIdx.x] = make_float4(a0, a1, a2, a3);
        __syncthreads();

        float4 A;
        if (threadIdx.x < 128) {
            float4 p0 = psum4[threadIdx.x], p1 = psum4[128 + threadIdx.x];
            A = make_float4(p0.x + p1.x, p0.y + p1.y, p0.z + p1.z, p0.w + p1.w);
            float sx = A.x * A.x, sy = A.y * A.y, sz = A.z * A.z, sw = A.w * A.w;
            for (int off = 32; off; off >>= 1) {
                sx += __shfl_down(sx, off); sy += __shfl_down(sy, off);
                sz += __shfl_down(sz, off); sw += __shfl_down(sw, off);
            }
            if ((threadIdx.x & 63) == 0) red4[threadIdx.x >> 6] = make_float4(sx, sy, sz, sw);
        }
        __syncthreads();
        if (threadIdx.x < 128) {
            float4 r0 = red4[0], r1 = red4[1];
            float ix = 1.f / fmaxf(sqrtf(r0.x + r1.x), 1e-12f);
            float iy = 1.f / fmaxf(sqrtf(r0.y + r1.y), 1e-12f);
            float iz = 1.f / fmaxf(sqrtf(r0.z + r1.z), 1e-12f);
            float iw = 1.f / fmaxf(sqrtf(r0.w + r1.w), 1e-12f);
            float* qb = q + (size_t)(b * 128 + d) * 4 * QLD + n;
            qb[0 * QLD] = A.x * ix;
            qb[1 * QLD] = A.y * iy;
            qb[2 * QLD] = A.z * iz;
            qb[3 * QLD] = A.w * iw;
        }
    }
}

// ---------------------------------------------------------------------------
// K2: qsp[b][t][d][s]; also zeroes barrier counters + loss accumulator for K3.
// K2 completes before k_tail in stream order => init is safely visible.
__global__ void k_qsp(const float* __restrict__ q, const float* __restrict__ wsg,
                      float* __restrict__ qsp, float* __restrict__ out,
                      int* __restrict__ bar) {
    if (blockIdx.x == 0 && threadIdx.x < 4) {
        bar[threadIdx.x] = 0;
        if (threadIdx.x == 0) out[0] = 0.f;
    }
    int tid = blockIdx.x * 256 + threadIdx.x;   // ((b*4+t)*128+d)*64+s
    int s = tid & 63;
    int d = (tid >> 6) & 127;
    int t = (tid >> 13) & 3;
    int b = tid >> 15;
    const float4* qrow = (const float4*)(q + (size_t)((b * 128 + d) * 4 + t) * QLD);
    const float4* wrow = (const float4*)(wsg + (size_t)((b * 4 + t) * 64 + s) * QLD);
    float acc = 0.f, den = 0.f;
    #pragma unroll
    for (int i = 0; i < 13; ++i) {
        float4 w = wrow[i];
        float4 qv = qrow[i];
        den += w.x + w.y + w.z + w.w;
        acc += qv.x * w.x + qv.y * w.y + qv.z * w.z + qv.w * w.w;
    }
    qsp[tid] = acc / (den + 1e-20f);
}

// ---------------------------------------------------------------------------
// Shared helpers for the fused tail.
// XOR-4-swizzled LDS matrix layout: element (r,k) of a 64x64 matrix lives at
// M[r*64 + (((k>>2)^(r&15))<<2)+(k&3)].

__device__ __forceinline__ void dump_mat(float* M, const float4* v) {
    #pragma unroll
    for (int it = 0; it < 4; ++it) {
        int idx = it * 256 + (int)threadIdx.x;
        int r = idx >> 4, c4 = (idx & 15) << 2;
        *(float4*)&M[r * 64 + (c4 ^ ((r & 15) << 2))] = v[it];
    }
}

// stage two 64x64 row-major global matrices into swizzled LDS (coalesced)
__device__ __forceinline__ void stage2(float* Ma, float* Mb,
                                       const float* __restrict__ Ga,
                                       const float* __restrict__ Gb) {
    const float4* ga = (const float4*)Ga;
    const float4* gb = (const float4*)Gb;
    float4 va[4], vb[4];
    #pragma unroll
    for (int it = 0; it < 4; ++it) {
        int idx = it * 256 + (int)threadIdx.x;
        va[it] = ga[idx];
        vb[it] = gb[idx];
    }
    dump_mat(Ma, va);
    dump_mat(Mb, vb);
}

// full-block mm (k=64, 4x4 tiles), swizzled LDS operands. C = Ra @ Rb^T.
__device__ __forceinline__ void mm256_sw(float* acc, const float* Ra, const float* Rb) {
    int tid = threadIdx.x;
    int nl = tid >> 4, ml = tid & 15;
    int sxa = nl << 2, sxb = ml << 2;
    #pragma unroll
    for (int i = 0; i < 16; ++i) acc[i] = 0.f;
    #pragma unroll 4
    for (int k0 = 0; k0 < 64; k0 += 4) {
        float4 av[4], bv[4];
        #pragma unroll
        for (int i = 0; i < 4; ++i)
            av[i] = *(const float4*)&Ra[(nl + 16 * i) * 64 + (k0 ^ sxa)];
        #pragma unroll
        for (int j = 0; j < 4; ++j)
            bv[j] = *(const float4*)&Rb[(ml + 16 * j) * 64 + (k0 ^ sxb)];
        #pragma unroll
        for (int i = 0; i < 4; ++i)
            #pragma unroll
            for (int j = 0; j < 4; ++j)
                acc[i * 4 + j] += av[i].x * bv[j].x + av[i].y * bv[j].y
                                + av[i].z * bv[j].z + av[i].w * bv[j].w;
    }
}

// store 64x64 result row-major to global (4 x 64B segments per store instr)
__device__ __forceinline__ void store_mat(float* __restrict__ G, const float* acc) {
    int nl = threadIdx.x >> 4, ml = threadIdx.x & 15;
    #pragma unroll
    for (int i = 0; i < 4; ++i)
        #pragma unroll
        for (int j = 0; j < 4; ++j)
            G[(nl + 16 * i) * 64 + ml + 16 * j] = acc[i * 4 + j];
}

// store aa + fused loss from registers (proven epilogue)
__device__ __forceinline__ void store_loss(const float* acc, float* __restrict__ aa,
                                           float* __restrict__ out, float* red) {
    int tid = threadIdx.x;
    int nl = tid >> 4, ml = tid & 15;
    #pragma unroll
    for (int i = 0; i < 4; ++i)
        #pragma unroll
        for (int j = 0; j < 4; ++j)
            aa[(nl + 16 * i) * 64 + (ml + 16 * j)] = acc[i * 4 + j];
    int l = tid & 63;
    float part = 0.f;
    #pragma unroll
    for (int i = 0; i < 4; ++i) {
        float rsum = acc[i * 4 + 0] + acc[i * 4 + 1] + acc[i * 4 + 2] + acc[i * 4 + 3];
        rsum += __shfl_down(rsum, 8, 16);
        rsum += __shfl_down(rsum, 4, 16);
        rsum += __shfl_down(rsum, 2, 16);
        rsum += __shfl_down(rsum, 1, 16);
        float dv = __shfl(acc[5 * i], (l & 48) | nl, 64);
        if ((l & 15) == 0) part += logf(rsum + 6.4e-19f) - logf(dv + 1e-20f);
    }
    for (int off = 32; off; off >>= 1) part += __shfl_down(part, off);
    if (l == 0) red[tid >> 6] = part;
    __syncthreads();
    if (tid == 0) atomicAdd(out, (red[0] + red[1] + red[2] + red[3]) * (1.f / 128.f));
}

// device-scope spin barrier; all gridDim blocks participate; single-use counter.
// 6 blocks are trivially co-resident on 256 CUs. (NOTE: grid-wide barriers at
// 256 blocks measured +50us on this chip — keep barrier grids tiny.)
__device__ __forceinline__ void gbar(int* cnt, int target) {
    __threadfence();
    __syncthreads();
    if (threadIdx.x == 0) {
        __hip_atomic_fetch_add(cnt, 1, __ATOMIC_ACQ_REL, __HIP_MEMORY_SCOPE_AGENT);
        while (__hip_atomic_load(cnt, __ATOMIC_ACQUIRE, __HIP_MEMORY_SCOPE_AGENT) < target)
            __builtin_amdgcn_s_sleep(2);
    }
    __syncthreads();
    __threadfence();
}

// ---------------------------------------------------------------------------
// K3: fused As+zero_softmax+chain. grid = 6, block = 256, 3 device barriers.
// phase A (6 blk): As/zero_softmax jobs (b,t); write only consumed layouts.
// phase B (4 blk): P_b = A12_0@A12_1 ; R1T_b = A21_0^T@A21_1^T
// phase C (6 blk): aa1_b = P@R1 (+loss) ; L_b = P@A12_2 ; RT_b = R1T@A21_2^T
// phase D (2 blk): aa2_b = L@R (+loss)
__global__ void __launch_bounds__(256, 1)
k_tail(const float* __restrict__ qsp,
       float* __restrict__ a12, float* __restrict__ a12T,
       float* __restrict__ a21, float* __restrict__ a21T,
       float* __restrict__ wsP, float* __restrict__ wsR1T,
       float* __restrict__ wsL, float* __restrict__ wsRT,
       float* __restrict__ out, int* __restrict__ bar) {
    __shared__ float SM[16384];           // 64 KB, aliased per phase
    const int tid = threadIdx.x;
    const int blk = blockIdx.x;

    // ---------------- phase A: As + zero_softmax (proven body) -------------
    {
        int t = blk % 3, b = blk / 3;
        float4* qaT4 = (float4*)SM;              // [64][32] swizzled (s-major)
        float4* qbT4 = (float4*)SM + 2048;
        {
            const float4* gA = (const float4*)(qsp + (size_t)(b * 4 + t) * 8192);
            const float4* gB = (const float4*)(qsp + (size_t)(b * 4 + t + 1) * 8192);
            float* qaF = (float*)qaT4;
            float* qbF = (float*)qbT4;
            #pragma unroll
            for (int it = 0; it < 8; ++it) {
                int idx = it * 256 + tid;           // float4 index over [d][s/4]
                int d = idx >> 4, s0 = (idx & 15) << 2;
                float4 va = gA[idx];
                float4 vb = gB[idx];
                int g = d >> 2, c = d & 3;
                #pragma unroll
                for (int u = 0; u < 4; ++u) {
                    int s = s0 + u;
                    int w = (s * 32 + (g ^ (s & 31))) * 4 + c;
                    float fa = (u == 0) ? va.x : (u == 1) ? va.y : (u == 2) ? va.z : va.w;
                    float fb = (u == 0) ? vb.x : (u == 1) ? vb.y : (u == 2) ? vb.z : vb.w;
                    qaF[w] = fa;
                    qbF[w] = fb;
                }
            }
        }
        __syncthreads();

        const int nl = tid >> 4, ml = tid & 15;
        float acc[16];
        #pragma unroll
        for (int i = 0; i < 16; ++i) acc[i] = 0.f;
        #pragma unroll 8
        for (int k4 = 0; k4 < 32; ++k4) {
            float4 av[4], bv[4];
            #pragma unroll
            for (int i = 0; i < 4; ++i) { int n = nl + 16 * i; av[i] = qaT4[n * 32 + (k4 ^ (n & 31))]; }
            #pragma unroll
            for (int j = 0; j < 4; ++j) { int m = ml + 16 * j; bv[j] = qbT4[m * 32 + (k4 ^ (m & 31))]; }
            #pragma unroll
            for (int i = 0; i < 4; ++i)
                #pragma unroll
                for (int j = 0; j < 4; ++j)
                    acc[i * 4 + j] += av[i].x * bv[j].x + av[i].y * bv[j].y
                                    + av[i].z * bv[j].z + av[i].w * bv[j].w;
        }
        __syncthreads();

        float* eb = (float*)qaT4;          // [64][65]
        float* rs = (float*)qbT4;          // [64]
        float* cs = rs + 64;               // [64]
        #pragma unroll
        for (int i = 0; i < 4; ++i)
            #pragma unroll
            for (int j = 0; j < 4; ++j) {
                int n = nl + 16 * i, m = ml + 16 * j;
                float x = acc[i * 4 + j] * (1.f / 0.07f);
                float e = expf(x) - 1.f;
                eb[n * 65 + m] = e * e;
            }
        __syncthreads();
        if (tid < 128) {
            int r = tid & 63; bool isrow = tid < 64;
            float a = 0.f;
            #pragma unroll
            for (int k = 0; k < 64; ++k) a += isrow ? eb[r * 65 + k] : eb[k * 65 + r];
            (isrow ? rs : cs)[r] = a + 1e-5f;
        }
        __syncthreads();
        // Only the orientations the chain consumes:
        //   t==0: A12_0 rows (Ra of P), A21_0^T rows (Ra of R1T)
        //   t>0 : A12_t^T rows (Rb), A21_t rows (Rb)
        float* p12  = a12  + (b * 3 + t) * 4096;
        float* p12T = a12T + (b * 3 + t) * 4096;
        float* p21  = a21  + (b * 3 + t) * 4096;
        float* p21T = a21T + (b * 3 + t) * 4096;
        #pragma unroll
        for (int i = 0; i < 4; ++i)
            #pragma unroll
            for (int j = 0; j < 4; ++j) {
                int n = nl + 16 * i, m = ml + 16 * j;
                float v   = eb[n * 65 + m];
                float v12 = v / rs[n];           // A12[n][m]
                float v21 = v / cs[m];           // A21[m][n]
                if (t == 0) {
                    p12 [n * 64 + m] = v12;      // A12_0 rows
                    p21T[n * 64 + m] = v21;      // A21_0^T rows
                } else {
                    p12T[m * 64 + n] = v12;      // A12_t^T rows
                    p21 [m * 64 + n] = v21;      // A21_t rows
                }
            }
    }
    gbar(bar + 0, 6);

    // ---------------- phase B: r1 (4 independent 64^3 mms) -----------------
    if (blk < 4) {
        int b = blk >> 1, which = blk & 1;
        float* Ma = SM;
        float* Mb = SM + 4096;
        if (which == 0) stage2(Ma, Mb, a12  + (b * 3 + 0) * 4096, a12T + (b * 3 + 1) * 4096);
        else            stage2(Ma, Mb, a21T + (b * 3 + 0) * 4096, a21  + (b * 3 + 1) * 4096);
        __syncthreads();
        float acc[16];
        mm256_sw(acc, Ma, Mb);                 // P = A12_0@A12_1 | R1T = A21_0^T@A21_1^T
        store_mat((which == 0 ? wsP : wsR1T) + b * 4096, acc);
    }
    gbar(bar + 1, 6);

    // ---------------- phase C: aa1 (+loss) and r2 (6 mms) ------------------
    {
        float* Ma = SM;
        float* Mb = SM + 4096;
        float* red = SM + 8192;
        if (blk < 2) {                          // aa1_b = P @ R1
            int b = blk;
            stage2(Ma, Mb, wsP + b * 4096, wsR1T + b * 4096);
            __syncthreads();
            float acc[16];
            mm256_sw(acc, Ma, Mb);
            store_loss(acc, out + 1 + b * 4096, out, red);
        } else if (blk < 4) {                   // L_b = P @ A12_2
            int b = blk - 2;
            stage2(Ma, Mb, wsP + b * 4096, a12T + (b * 3 + 2) * 4096);
            __syncthreads();
            float acc[16];
            mm256_sw(acc, Ma, Mb);
            store_mat(wsL + b * 4096, acc);
        } else {                                // RT_b = R1T @ A21_2^T = (A21_2@R1)^T
            int b = blk - 4;
            stage2(Ma, Mb, wsR1T + b * 4096, a21 + (b * 3 + 2) * 4096);
            __syncthreads();
            float acc[16];
            mm256_sw(acc, Ma, Mb);
            store_mat(wsRT + b * 4096, acc);
        }
    }
    gbar(bar + 2, 6);

    // ---------------- phase D: aa2 (+loss), 2 mms --------------------------
    if (blk < 2) {
        int b = blk;
        float* Ma = SM;
        float* Mb = SM + 4096;
        float* red = SM + 8192;
        stage2(Ma, Mb, wsL + b * 4096, wsRT + b * 4096);
        __syncthreads();
        float acc[16];
        mm256_sw(acc, Ma, Mb);                  // aa2 = L @ R
        store_loss(acc, out + 1 + (2 + b) * 4096, out, red);
    }
}

// ---------------------------------------------------------------------------
extern "C" void kernel_launch(void* const* d_in, const int* in_sizes, int n_in,
                              void* d_out, int out_size, void* d_ws, size_t ws_size,
                              hipStream_t stream) {
    const float* feats = (const float*)d_in[0];
    const float* Wh    = (const float*)d_in[1];
    const int*   mask  = (const int*)d_in[2];
    float* out = (float*)d_out;
    float* ws  = (float*)d_ws;

    float* ws_sums = ws + OFF_WS;
    float* q       = ws + OFF_Q;
    float* qsp     = ws + OFF_QSP;
    float* a12     = ws + OFF_A12;
    float* a12T    = ws + OFF_A12T;
    float* a21     = ws + OFF_A21;
    float* a21T    = ws + OFF_A21T;
    float* wsP     = ws + OFF_P;
    float* wsR1T   = ws + OFF_R1T;
    float* wsL     = ws + OFF_L;
    float* wsRT    = ws + OFF_RT;
    int*   bar     = (int*)(ws + OFF_BAR);

    k_front<<<392 + 2 * NWIN, 256, 0, stream>>>(mask, feats, Wh, ws_sums, q);
    k_qsp<<<256, 256, 0, stream>>>(q, ws_sums, qsp, out, bar);
    k_tail<<<6, 256, 0, stream>>>(qsp, a12, a12T, a21, a21T,
                                  wsP, wsR1T, wsL, wsRT, out, bar);
}

// Round 4
// 110.700 us; speedup vs baseline: 1.2916x; 1.0869x over previous
//
#include <hip/hip_runtime.h>
#include <hip/hip_bf16.h>

// Problem constants (fixed by reference setup_inputs)
constexpr int NWIN = 49;     // 7x7 windows
constexpr int QLD  = 52;     // padded row length for 49-length rows (13 float4)

// workspace layout (float offsets)
constexpr int OFF_WS   = 0;            // [8][64][52]      = 26624 (bt, s, win)
constexpr int OFF_Q    = 26624;        // [2][128][4][52]  = 53248 (b, d, t, n)
constexpr int OFF_QSP  = 79872;        // [2][4][128][64]  = 65536 (b, t, d, s)
constexpr int OFF_A12  = 145408;       // [2][3][64][64]  (only t=0 written)
constexpr int OFF_A12T = 169984;       // (only t=1,2 written)
constexpr int OFF_A21  = 194560;       // (only t=1,2 written)
constexpr int OFF_A21T = 219136;       // (only t=0 written)
constexpr int OFF_R1T  = 251904;       // [2][4096]  R1^T = A21_0^T @ A21_1^T
constexpr int OFF_L    = 260096;       // [2][4096]  L    = P @ A12_2
constexpr int OFF_BAR  = 276480;       // 4 ints (barrier counters)

// ---------------------------------------------------------------------------
// K1: fused front end — blocks [0,392): scatter; blocks [392,490): q head.
// (exact round-1 proven body: LDS-staged feats in the q head)
__global__ void __launch_bounds__(256, 1)
k_front(const int* __restrict__ mask, const float* __restrict__ feats,
        const float* __restrict__ Wh, float* __restrict__ ws, float* __restrict__ q) {
    if (blockIdx.x < 392) {
        int win = blockIdx.x % NWIN;
        int bt  = blockIdx.x / NWIN;
        int wy = win / 7, wx = win % 7;
        __shared__ float loc[64];
        if (threadIdx.x < 64) loc[threadIdx.x] = 0.f;
        __syncthreads();
        const int* base = mask + bt * 65536 + (wy * 32) * 256 + wx * 32;
        #pragma unroll
        for (int it = 0; it < 16; ++it) {
            int idx = it * 256 + (int)threadIdx.x;
            int r = idx >> 6, c = idx & 63;
            int s = base[r * 256 + c];
            int y = wy * 32 + r, x = wx * 32 + c;
            float w = 1.f;
            if (y >= 32 && y < 224) w *= 0.5f;   // row coverage = 2
            if (x >= 32 && x < 224) w *= 0.5f;   // col coverage = 2
            atomicAdd(&loc[s], w);
        }
        __syncthreads();
        if (threadIdx.x < 64) {
            ws[(bt * 64 + (int)threadIdx.x) * QLD + win] = loc[threadIdx.x];
        } else if (win == 0) {
            int s = threadIdx.x & 63;
            int col = 49 + (int)(threadIdx.x >> 6) - 1;   // 49,50,51
            ws[(bt * 64 + s) * QLD + col] = 0.f;
        }
    } else {
        // q[b][d][t][n] = normalize_d(feats[b,n,:,t] @ Wh[:,d])
        // LDS staging is PROVEN faster than uniform global loads here
        // (R3 measured +5.5us without it: uniform global loads are
        // latency-chained; LDS broadcast reads hide across waves).
        int bid = blockIdx.x - 392;
        int n = bid % NWIN, b = bid / NWIN;
        __shared__ float4 f4[512];        // feats[c][t] as float4 over t
        __shared__ float4 psum4[256];
        __shared__ float4 red4[2];
        const float4* fp4 = (const float4*)(feats + (size_t)(b * NWIN + n) * 2048);
        for (int i = threadIdx.x; i < 512; i += 256) f4[i] = fp4[i];
        __syncthreads();

        int d = threadIdx.x & 127, ch = threadIdx.x >> 7;
        float a0 = 0.f, a1 = 0.f, a2 = 0.f, a3 = 0.f;
        const float* wp = Wh + d;
        int c0 = ch * 256;
        #pragma unroll 8
        for (int c = c0; c < c0 + 256; ++c) {
            float w = wp[c * 128];
            float4 fv = f4[c];
            a0 += fv.x * w; a1 += fv.y * w; a2 += fv.z * w; a3 += fv.w * w;
        }
        psum4[threadIdx.x] = make_float4(a0, a1, a2, a3);
        __syncthreads();

        float4 A;
        if (threadIdx.x < 128) {
            float4 p0 = psum4[threadIdx.x], p1 = psum4[128 + threadIdx.x];
            A = make_float4(p0.x + p1.x, p0.y + p1.y, p0.z + p1.z, p0.w + p1.w);
            float sx = A.x * A.x, sy = A.y * A.y, sz = A.z * A.z, sw = A.w * A.w;
            for (int off = 32; off; off >>= 1) {
                sx += __shfl_down(sx, off); sy += __shfl_down(sy, off);
                sz += __shfl_down(sz, off); sw += __shfl_down(sw, off);
            }
            if ((threadIdx.x & 63) == 0) red4[threadIdx.x >> 6] = make_float4(sx, sy, sz, sw);
        }
        __syncthreads();
        if (threadIdx.x < 128) {
            float4 r0 = red4[0], r1 = red4[1];
            float ix = 1.f / fmaxf(sqrtf(r0.x + r1.x), 1e-12f);
            float iy = 1.f / fmaxf(sqrtf(r0.y + r1.y), 1e-12f);
            float iz = 1.f / fmaxf(sqrtf(r0.z + r1.z), 1e-12f);
            float iw = 1.f / fmaxf(sqrtf(r0.w + r1.w), 1e-12f);
            float* qb = q + (size_t)(b * 128 + d) * 4 * QLD + n;
            qb[0 * QLD] = A.x * ix;
            qb[1 * QLD] = A.y * iy;
            qb[2 * QLD] = A.z * iz;
            qb[3 * QLD] = A.w * iw;
        }
    }
}

// ---------------------------------------------------------------------------
// K2: qsp[b][t][d][s]; also zeroes barrier counters + loss accumulator for K3.
__global__ void k_qsp(const float* __restrict__ q, const float* __restrict__ wsg,
                      float* __restrict__ qsp, float* __restrict__ out,
                      int* __restrict__ bar) {
    if (blockIdx.x == 0 && threadIdx.x < 4) {
        bar[threadIdx.x] = 0;
        if (threadIdx.x == 0) out[0] = 0.f;
    }
    int tid = blockIdx.x * 256 + threadIdx.x;   // ((b*4+t)*128+d)*64+s
    int s = tid & 63;
    int d = (tid >> 6) & 127;
    int t = (tid >> 13) & 3;
    int b = tid >> 15;
    const float4* qrow = (const float4*)(q + (size_t)((b * 128 + d) * 4 + t) * QLD);
    const float4* wrow = (const float4*)(wsg + (size_t)((b * 4 + t) * 64 + s) * QLD);
    float acc = 0.f, den = 0.f;
    #pragma unroll
    for (int i = 0; i < 13; ++i) {
        float4 w = wrow[i];
        float4 qv = qrow[i];
        den += w.x + w.y + w.z + w.w;
        acc += qv.x * w.x + qv.y * w.y + qv.z * w.z + qv.w * w.w;
    }
    qsp[tid] = acc / (den + 1e-20f);
}

// ---------------------------------------------------------------------------
// Shared helpers. XOR-4-swizzled LDS matrix layout: element (r,k) lives at
// M[r*64 + (((k>>2)^(r&15))<<2)+(k&3)].

__device__ __forceinline__ void dump_mat(float* M, const float4* v) {
    #pragma unroll
    for (int it = 0; it < 4; ++it) {
        int idx = it * 256 + (int)threadIdx.x;
        int r = idx >> 4, c4 = (idx & 15) << 2;
        *(float4*)&M[r * 64 + (c4 ^ ((r & 15) << 2))] = v[it];
    }
}

// stage one 64x64 row-major global matrix into swizzled LDS (coalesced)
__device__ __forceinline__ void stage1(float* M, const float* __restrict__ G) {
    const float4* g = (const float4*)G;
    float4 v[4];
    #pragma unroll
    for (int it = 0; it < 4; ++it) v[it] = g[it * 256 + (int)threadIdx.x];
    dump_mat(M, v);
}

__device__ __forceinline__ void stage2(float* Ma, float* Mb,
                                       const float* __restrict__ Ga,
                                       const float* __restrict__ Gb) {
    const float4* ga = (const float4*)Ga;
    const float4* gb = (const float4*)Gb;
    float4 va[4], vb[4];
    #pragma unroll
    for (int it = 0; it < 4; ++it) {
        int idx = it * 256 + (int)threadIdx.x;
        va[it] = ga[idx];
        vb[it] = gb[idx];
    }
    dump_mat(Ma, va);
    dump_mat(Mb, vb);
}

// full-block mm (k=64, 4x4 tiles), swizzled LDS operands. acc[n][m] = sum_k Ra[n][k]*Rb[m][k]
__device__ __forceinline__ void mm256_sw(float* acc, const float* Ra, const float* Rb) {
    int tid = threadIdx.x;
    int nl = tid >> 4, ml = tid & 15;
    int sxa = nl << 2, sxb = ml << 2;
    #pragma unroll
    for (int i = 0; i < 16; ++i) acc[i] = 0.f;
    #pragma unroll 4
    for (int k0 = 0; k0 < 64; k0 += 4) {
        float4 av[4], bv[4];
        #pragma unroll
        for (int i = 0; i < 4; ++i)
            av[i] = *(const float4*)&Ra[(nl + 16 * i) * 64 + (k0 ^ sxa)];
        #pragma unroll
        for (int j = 0; j < 4; ++j)
            bv[j] = *(const float4*)&Rb[(ml + 16 * j) * 64 + (k0 ^ sxb)];
        #pragma unroll
        for (int i = 0; i < 4; ++i)
            #pragma unroll
            for (int j = 0; j < 4; ++j)
                acc[i * 4 + j] += av[i].x * bv[j].x + av[i].y * bv[j].y
                                + av[i].z * bv[j].z + av[i].w * bv[j].w;
    }
}

// write full-block acc rows (acc[n][k] layout) into swizzled LDS
__device__ __forceinline__ void wr256_sw(float* M, const float* acc) {
    int nl = threadIdx.x >> 4, ml = threadIdx.x & 15;
    #pragma unroll
    for (int i = 0; i < 4; ++i)
        #pragma unroll
        for (int j = 0; j < 4; ++j) {
            int r = nl + 16 * i, k = ml + 16 * j;
            M[r * 64 + (((k & ~3) ^ ((r & 15) << 2)) | (k & 3))] = acc[i * 4 + j];
        }
}

// store 64x64 result row-major to global
__device__ __forceinline__ void store_mat(float* __restrict__ G, const float* acc) {
    int nl = threadIdx.x >> 4, ml = threadIdx.x & 15;
    #pragma unroll
    for (int i = 0; i < 4; ++i)
        #pragma unroll
        for (int j = 0; j < 4; ++j)
            G[(nl + 16 * i) * 64 + ml + 16 * j] = acc[i * 4 + j];
}

// store aa + fused loss from registers (proven epilogue)
__device__ __forceinline__ void store_loss(const float* acc, float* __restrict__ aa,
                                           float* __restrict__ out, float* red) {
    int tid = threadIdx.x;
    int nl = tid >> 4, ml = tid & 15;
    #pragma unroll
    for (int i = 0; i < 4; ++i)
        #pragma unroll
        for (int j = 0; j < 4; ++j)
            aa[(nl + 16 * i) * 64 + (ml + 16 * j)] = acc[i * 4 + j];
    int l = tid & 63;
    float part = 0.f;
    #pragma unroll
    for (int i = 0; i < 4; ++i) {
        float rsum = acc[i * 4 + 0] + acc[i * 4 + 1] + acc[i * 4 + 2] + acc[i * 4 + 3];
        rsum += __shfl_down(rsum, 8, 16);
        rsum += __shfl_down(rsum, 4, 16);
        rsum += __shfl_down(rsum, 2, 16);
        rsum += __shfl_down(rsum, 1, 16);
        float dv = __shfl(acc[5 * i], (l & 48) | nl, 64);
        if ((l & 15) == 0) part += logf(rsum + 6.4e-19f) - logf(dv + 1e-20f);
    }
    for (int off = 32; off; off >>= 1) part += __shfl_down(part, off);
    if (l == 0) red[tid >> 6] = part;
    __syncthreads();
    if (tid == 0) atomicAdd(out, (red[0] + red[1] + red[2] + red[3]) * (1.f / 128.f));
}

// device-scope spin barrier; single-use counter. Keep barrier grids TINY:
// 256-block version measured +50us (R2).
__device__ __forceinline__ void gbar(int* cnt, int target) {
    __threadfence();
    __syncthreads();
    if (threadIdx.x == 0) {
        __hip_atomic_fetch_add(cnt, 1, __ATOMIC_ACQ_REL, __HIP_MEMORY_SCOPE_AGENT);
        while (__hip_atomic_load(cnt, __ATOMIC_ACQUIRE, __HIP_MEMORY_SCOPE_AGENT) < target)
            __builtin_amdgcn_s_sleep(2);
    }
    __syncthreads();
    __threadfence();
}

// ---------------------------------------------------------------------------
// K3: fused As+zero_softmax+chain. grid = 6, block = 256, TWO device barriers.
// phase A  (6 blk): As/zero_softmax job (b,t); write only consumed layouts.
//   bar0(6); blocks 4,5 exit after arrival.
// phase B' (4 blk): blk 2b+0: P=A12_0@A12_1 (kept in LDS), L=P@A12_2 -> wsL
//                   blk 2b+1: R1T=A21_0^T@A21_1^T (LDS + wsR1T), RT=R1T@A21_2^T (LDS)
//   bar1(4)
// phase C' (4 blk): blk 2b+0: aa1_b = P @ R1 (+loss)   [P local, R1T staged]
//                   blk 2b+1: aa2_b = L @ R  (+loss)   [RT local, L staged]
__global__ void __launch_bounds__(256, 1)
k_tail(const float* __restrict__ qsp,
       float* __restrict__ a12, float* __restrict__ a12T,
       float* __restrict__ a21, float* __restrict__ a21T,
       float* __restrict__ wsR1T, float* __restrict__ wsL,
       float* __restrict__ out, int* __restrict__ bar) {
    __shared__ float SM[16384];           // 64 KB, aliased per phase
    float* M0 = SM;
    float* M1 = SM + 4096;
    float* M2 = SM + 8192;
    float* M3 = SM + 12288;
    const int tid = threadIdx.x;
    const int blk = blockIdx.x;

    // ---------------- phase A: As + zero_softmax (proven body) -------------
    {
        int t = blk % 3, b = blk / 3;
        float4* qaT4 = (float4*)SM;              // [64][32] swizzled (s-major)
        float4* qbT4 = (float4*)SM + 2048;
        {
            const float4* gA = (const float4*)(qsp + (size_t)(b * 4 + t) * 8192);
            const float4* gB = (const float4*)(qsp + (size_t)(b * 4 + t + 1) * 8192);
            float* qaF = (float*)qaT4;
            float* qbF = (float*)qbT4;
            #pragma unroll
            for (int it = 0; it < 8; ++it) {
                int idx = it * 256 + tid;           // float4 index over [d][s/4]
                int d = idx >> 4, s0 = (idx & 15) << 2;
                float4 va = gA[idx];
                float4 vb = gB[idx];
                int g = d >> 2, c = d & 3;
                #pragma unroll
                for (int u = 0; u < 4; ++u) {
                    int s = s0 + u;
                    int w = (s * 32 + (g ^ (s & 31))) * 4 + c;
                    float fa = (u == 0) ? va.x : (u == 1) ? va.y : (u == 2) ? va.z : va.w;
                    float fb = (u == 0) ? vb.x : (u == 1) ? vb.y : (u == 2) ? vb.z : vb.w;
                    qaF[w] = fa;
                    qbF[w] = fb;
                }
            }
        }
        __syncthreads();

        const int nl = tid >> 4, ml = tid & 15;
        float acc[16];
        #pragma unroll
        for (int i = 0; i < 16; ++i) acc[i] = 0.f;
        #pragma unroll 8
        for (int k4 = 0; k4 < 32; ++k4) {
            float4 av[4], bv[4];
            #pragma unroll
            for (int i = 0; i < 4; ++i) { int n = nl + 16 * i; av[i] = qaT4[n * 32 + (k4 ^ (n & 31))]; }
            #pragma unroll
            for (int j = 0; j < 4; ++j) { int m = ml + 16 * j; bv[j] = qbT4[m * 32 + (k4 ^ (m & 31))]; }
            #pragma unroll
            for (int i = 0; i < 4; ++i)
                #pragma unroll
                for (int j = 0; j < 4; ++j)
                    acc[i * 4 + j] += av[i].x * bv[j].x + av[i].y * bv[j].y
                                    + av[i].z * bv[j].z + av[i].w * bv[j].w;
        }
        __syncthreads();

        float* eb = (float*)qaT4;          // [64][65]
        float* rs = (float*)qbT4;          // [64]
        float* cs = rs + 64;               // [64]
        #pragma unroll
        for (int i = 0; i < 4; ++i)
            #pragma unroll
            for (int j = 0; j < 4; ++j) {
                int n = nl + 16 * i, m = ml + 16 * j;
                float x = acc[i * 4 + j] * (1.f / 0.07f);
                float e = expf(x) - 1.f;
                eb[n * 65 + m] = e * e;
            }
        __syncthreads();
        if (tid < 128) {
            int r = tid & 63; bool isrow = tid < 64;
            float a = 0.f;
            #pragma unroll
            for (int k = 0; k < 64; ++k) a += isrow ? eb[r * 65 + k] : eb[k * 65 + r];
            (isrow ? rs : cs)[r] = a + 1e-5f;
        }
        __syncthreads();
        // Only the orientations the chain consumes:
        //   t==0: A12_0 rows, A21_0^T rows;  t>0: A12_t^T rows, A21_t rows
        float* p12  = a12  + (b * 3 + t) * 4096;
        float* p12T = a12T + (b * 3 + t) * 4096;
        float* p21  = a21  + (b * 3 + t) * 4096;
        float* p21T = a21T + (b * 3 + t) * 4096;
        #pragma unroll
        for (int i = 0; i < 4; ++i)
            #pragma unroll
            for (int j = 0; j < 4; ++j) {
                int n = nl + 16 * i, m = ml + 16 * j;
                float v   = eb[n * 65 + m];
                float v12 = v / rs[n];           // A12[n][m]
                float v21 = v / cs[m];           // A21[m][n]
                if (t == 0) {
                    p12 [n * 64 + m] = v12;      // A12_0 rows
                    p21T[n * 64 + m] = v21;      // A21_0^T rows
                } else {
                    p12T[m * 64 + n] = v12;      // A12_t^T rows
                    p21 [m * 64 + n] = v21;      // A21_t rows
                }
            }
    }
    gbar(bar + 0, 6);
    if (blk >= 4) return;                 // blocks 4,5 done (arrived at bar0)

    // ---------------- phase B': 2 mms per block, intermediates stay in LDS -
    int b = blk >> 1, odd = blk & 1;
    if (!odd) {
        // P = A12_0 @ A12_1 (keep in M2); L = P @ A12_2 -> wsL
        stage2(M0, M1, a12 + (b * 3 + 0) * 4096, a12T + (b * 3 + 1) * 4096);
        __syncthreads();
        float acc[16];
        mm256_sw(acc, M0, M1);                    // P
        wr256_sw(M2, acc);                        // P rows, local
        stage1(M3, a12T + (b * 3 + 2) * 4096);    // A12_2^T rows
        __syncthreads();
        float acc2[16];
        mm256_sw(acc2, M2, M3);                   // L = P @ A12_2
        store_mat(wsL + b * 4096, acc2);          // partner needs L
    } else {
        // R1T = A21_0^T @ A21_1^T (keep in M2 + publish); RT = R1T @ A21_2^T (keep in M1)
        stage2(M0, M1, a21T + (b * 3 + 0) * 4096, a21 + (b * 3 + 1) * 4096);
        __syncthreads();
        float acc[16];
        mm256_sw(acc, M0, M1);                    // R1T (rows n,k: R1T[n][k]=R1[k][n])
        store_mat(wsR1T + b * 4096, acc);         // partner needs R1T
        wr256_sw(M2, acc);                        // R1T rows, local
        stage1(M3, a21 + (b * 3 + 2) * 4096);     // A21_2 rows
        __syncthreads();
        float acc2[16];
        mm256_sw(acc2, M2, M3);                   // RT[n][m] = (A21_2@R1)^T
        wr256_sw(M1, acc2);                       // RT rows, local (Rb of aa2)
    }
    gbar(bar + 1, 4);

    // ---------------- phase C': final mms + fused loss ---------------------
    if (!odd) {
        // aa1_b = P @ R1 : Ra = M2 (P, resident), Rb = R1T_b staged
        stage1(M3, wsR1T + b * 4096);
        __syncthreads();
        float acc[16];
        mm256_sw(acc, M2, M3);
        store_loss(acc, out + 1 + b * 4096, out, M0);
    } else {
        // aa2_b = L @ R : Ra = L_b staged, Rb = M1 (RT, resident)
        stage1(M0, wsL + b * 4096);
        __syncthreads();
        float acc[16];
        mm256_sw(acc, M0, M1);
        store_loss(acc, out + 1 + (2 + b) * 4096, out, M2);
    }
}

// ---------------------------------------------------------------------------
extern "C" void kernel_launch(void* const* d_in, const int* in_sizes, int n_in,
                              void* d_out, int out_size, void* d_ws, size_t ws_size,
                              hipStream_t stream) {
    const float* feats = (const float*)d_in[0];
    const float* Wh    = (const float*)d_in[1];
    const int*   mask  = (const int*)d_in[2];
    float* out = (float*)d_out;
    float* ws  = (float*)d_ws;

    float* ws_sums = ws + OFF_WS;
    float* q       = ws + OFF_Q;
    float* qsp     = ws + OFF_QSP;
    float* a12     = ws + OFF_A12;
    float* a12T    = ws + OFF_A12T;
    float* a21     = ws + OFF_A21;
    float* a21T    = ws + OFF_A21T;
    float* wsR1T   = ws + OFF_R1T;
    float* wsL     = ws + OFF_L;
    int*   bar     = (int*)(ws + OFF_BAR);

    k_front<<<392 + 2 * NWIN, 256, 0, stream>>>(mask, feats, Wh, ws_sums, q);
    k_qsp<<<256, 256, 0, stream>>>(q, ws_sums, qsp, out, bar);
    k_tail<<<6, 256, 0, stream>>>(qsp, a12, a12T, a21, a21T,
                                  wsR1T, wsL, out, bar);
}

// Round 5
// 107.322 us; speedup vs baseline: 1.3323x; 1.0315x over previous
//
#include <hip/hip_runtime.h>
#include <hip/hip_bf16.h>

// Problem constants (fixed by reference setup_inputs)
constexpr int NWIN = 49;     // 7x7 windows
constexpr int QLD  = 52;     // padded row length for 49-length rows (13 float4)

// workspace layout (float offsets)
constexpr int OFF_WS   = 0;            // [8][64][52]      = 26624 (bt, s, win)
constexpr int OFF_Q    = 26624;        // [2][128][4][52]  = 53248 (b, d, t, n)
constexpr int OFF_QSP  = 79872;        // [2][4][8192]     swizzled (b, t, w)
constexpr int OFF_A12  = 145408;       // [2][3][64][64]  (only t=0 written)
constexpr int OFF_A12T = 169984;       // (only t=1,2 written)
constexpr int OFF_A21  = 194560;       // (only t=1,2 written)
constexpr int OFF_A21T = 219136;       // (only t=0 written)
constexpr int OFF_R1T  = 251904;       // [2][4096]  R1^T = A21_0^T @ A21_1^T
constexpr int OFF_L    = 260096;       // [2][4096]  L    = P @ A12_2
constexpr int OFF_BAR  = 276480;       // 4 ints (barrier counters)

// ---------------------------------------------------------------------------
// K1: fused front end — blocks [0,392): scatter; blocks [392,490): q head.
__global__ void __launch_bounds__(256, 1)
k_front(const int* __restrict__ mask, const float* __restrict__ feats,
        const float* __restrict__ Wh, float* __restrict__ ws, float* __restrict__ q) {
    if (blockIdx.x < 392) {
        int win = blockIdx.x % NWIN;
        int bt  = blockIdx.x / NWIN;
        int wy = win / 7, wx = win % 7;
        __shared__ float loc[64];
        if (threadIdx.x < 64) loc[threadIdx.x] = 0.f;
        __syncthreads();
        const int* base = mask + bt * 65536 + (wy * 32) * 256 + wx * 32;
        #pragma unroll
        for (int it = 0; it < 16; ++it) {
            int idx = it * 256 + (int)threadIdx.x;
            int r = idx >> 6, c = idx & 63;
            int s = base[r * 256 + c];
            int y = wy * 32 + r, x = wx * 32 + c;
            float w = 1.f;
            if (y >= 32 && y < 224) w *= 0.5f;   // row coverage = 2
            if (x >= 32 && x < 224) w *= 0.5f;   // col coverage = 2
            atomicAdd(&loc[s], w);
        }
        __syncthreads();
        if (threadIdx.x < 64) {
            ws[(bt * 64 + (int)threadIdx.x) * QLD + win] = loc[threadIdx.x];
        } else if (win == 0) {
            int s = threadIdx.x & 63;
            int col = 49 + (int)(threadIdx.x >> 6) - 1;   // 49,50,51
            ws[(bt * 64 + s) * QLD + col] = 0.f;
        }
    } else {
        // q[b][d][t][n] = normalize_d(feats[b,n,:,t] @ Wh[:,d])
        // LDS staging proven (R3: removing it cost +5.5us). DS-issue relief:
        // 2 d per thread x 4 c-quarters -> 128 ds broadcasts/wave (was 256),
        // same FMA + VMEM totals.
        int bid = blockIdx.x - 392;
        int n = bid % NWIN, b = bid / NWIN;
        __shared__ float4 f4[512];        // feats[c][t] as float4 over t
        __shared__ float4 psum4[512];     // [ch(4)][d(128)] partials
        __shared__ float4 red4[2];
        const float4* fp4 = (const float4*)(feats + (size_t)(b * NWIN + n) * 2048);
        for (int i = threadIdx.x; i < 512; i += 256) f4[i] = fp4[i];
        __syncthreads();

        int dl = threadIdx.x & 63, ch = threadIdx.x >> 6;   // ch in 0..3
        float a0 = 0.f, a1 = 0.f, a2 = 0.f, a3 = 0.f;       // d = dl
        float b0 = 0.f, b1 = 0.f, b2 = 0.f, b3 = 0.f;       // d = dl + 64
        const float* wpa = Wh + dl;
        const float* wpb = Wh + dl + 64;
        int c0 = ch * 128;
        #pragma unroll 8
        for (int c = c0; c < c0 + 128; ++c) {
            float w0 = wpa[c * 128];
            float w1 = wpb[c * 128];
            float4 fv = f4[c];
            a0 += fv.x * w0; a1 += fv.y * w0; a2 += fv.z * w0; a3 += fv.w * w0;
            b0 += fv.x * w1; b1 += fv.y * w1; b2 += fv.z * w1; b3 += fv.w * w1;
        }
        psum4[ch * 128 + dl]      = make_float4(a0, a1, a2, a3);
        psum4[ch * 128 + dl + 64] = make_float4(b0, b1, b2, b3);
        __syncthreads();

        float4 A;
        if (threadIdx.x < 128) {
            float4 p0 = psum4[threadIdx.x],       p1 = psum4[128 + threadIdx.x];
            float4 p2 = psum4[256 + threadIdx.x], p3 = psum4[384 + threadIdx.x];
            A = make_float4((p0.x + p1.x) + (p2.x + p3.x),
                            (p0.y + p1.y) + (p2.y + p3.y),
                            (p0.z + p1.z) + (p2.z + p3.z),
                            (p0.w + p1.w) + (p2.w + p3.w));
            float sx = A.x * A.x, sy = A.y * A.y, sz = A.z * A.z, sw = A.w * A.w;
            for (int off = 32; off; off >>= 1) {
                sx += __shfl_down(sx, off); sy += __shfl_down(sy, off);
                sz += __shfl_down(sz, off); sw += __shfl_down(sw, off);
            }
            if ((threadIdx.x & 63) == 0) red4[threadIdx.x >> 6] = make_float4(sx, sy, sz, sw);
        }
        __syncthreads();
        if (threadIdx.x < 128) {
            float4 r0 = red4[0], r1 = red4[1];
            float ix = 1.f / fmaxf(sqrtf(r0.x + r1.x), 1e-12f);
            float iy = 1.f / fmaxf(sqrtf(r0.y + r1.y), 1e-12f);
            float iz = 1.f / fmaxf(sqrtf(r0.z + r1.z), 1e-12f);
            float iw = 1.f / fmaxf(sqrtf(r0.w + r1.w), 1e-12f);
            float* qb = q + (size_t)(b * 128 + (int)threadIdx.x) * 4 * QLD + n;
            qb[0 * QLD] = A.x * ix;
            qb[1 * QLD] = A.y * iy;
            qb[2 * QLD] = A.z * iz;
            qb[3 * QLD] = A.w * iw;
        }
    }
}

// ---------------------------------------------------------------------------
// K2: qsp, stored directly in the phase-A swizzled layout:
//   qsp[(b,t)*8192 + w],  w = (s*32 + ((d>>2) ^ (s&31)))*4 + (d&3)
// so phase-A staging is a pure float4 copy. Also zeroes barrier counters +
// loss accumulator (stream order guarantees visibility before k_tail).
__global__ void k_qsp(const float* __restrict__ q, const float* __restrict__ wsg,
                      float* __restrict__ qsp, float* __restrict__ out,
                      int* __restrict__ bar) {
    if (blockIdx.x == 0 && threadIdx.x < 4) {
        bar[threadIdx.x] = 0;
        if (threadIdx.x == 0) out[0] = 0.f;
    }
    int gid = blockIdx.x * 256 + threadIdx.x;   // [b:1][t:2][s:6][d:7]
    int d = gid & 127;
    int s = (gid >> 7) & 63;
    int t = (gid >> 13) & 3;
    int b = gid >> 15;
    const float4* qrow = (const float4*)(q + (size_t)((b * 128 + d) * 4 + t) * QLD);
    const float4* wrow = (const float4*)(wsg + (size_t)((b * 4 + t) * 64 + s) * QLD);
    float acc = 0.f, den = 0.f;
    #pragma unroll
    for (int i = 0; i < 13; ++i) {
        float4 w = wrow[i];
        float4 qv = qrow[i];
        den += w.x + w.y + w.z + w.w;
        acc += qv.x * w.x + qv.y * w.y + qv.z * w.z + qv.w * w.w;
    }
    int w = (s * 32 + ((d >> 2) ^ (s & 31))) * 4 + (d & 3);
    qsp[(size_t)(b * 4 + t) * 8192 + w] = acc / (den + 1e-20f);
}

// ---------------------------------------------------------------------------
// Shared helpers. XOR-4-swizzled LDS matrix layout: element (r,k) lives at
// M[r*64 + (((k>>2)^(r&15))<<2)+(k&3)].

__device__ __forceinline__ void dump_mat(float* M, const float4* v) {
    #pragma unroll
    for (int it = 0; it < 4; ++it) {
        int idx = it * 256 + (int)threadIdx.x;
        int r = idx >> 4, c4 = (idx & 15) << 2;
        *(float4*)&M[r * 64 + (c4 ^ ((r & 15) << 2))] = v[it];
    }
}

// stage one 64x64 row-major global matrix into swizzled LDS (coalesced)
__device__ __forceinline__ void stage1(float* M, const float* __restrict__ G) {
    const float4* g = (const float4*)G;
    float4 v[4];
    #pragma unroll
    for (int it = 0; it < 4; ++it) v[it] = g[it * 256 + (int)threadIdx.x];
    dump_mat(M, v);
}

__device__ __forceinline__ void stage2(float* Ma, float* Mb,
                                       const float* __restrict__ Ga,
                                       const float* __restrict__ Gb) {
    const float4* ga = (const float4*)Ga;
    const float4* gb = (const float4*)Gb;
    float4 va[4], vb[4];
    #pragma unroll
    for (int it = 0; it < 4; ++it) {
        int idx = it * 256 + (int)threadIdx.x;
        va[it] = ga[idx];
        vb[it] = gb[idx];
    }
    dump_mat(Ma, va);
    dump_mat(Mb, vb);
}

// full-block mm (k=64, 4x4 tiles), swizzled LDS operands. acc[n][m] = sum_k Ra[n][k]*Rb[m][k]
__device__ __forceinline__ void mm256_sw(float* acc, const float* Ra, const float* Rb) {
    int tid = threadIdx.x;
    int nl = tid >> 4, ml = tid & 15;
    int sxa = nl << 2, sxb = ml << 2;
    #pragma unroll
    for (int i = 0; i < 16; ++i) acc[i] = 0.f;
    #pragma unroll 4
    for (int k0 = 0; k0 < 64; k0 += 4) {
        float4 av[4], bv[4];
        #pragma unroll
        for (int i = 0; i < 4; ++i)
            av[i] = *(const float4*)&Ra[(nl + 16 * i) * 64 + (k0 ^ sxa)];
        #pragma unroll
        for (int j = 0; j < 4; ++j)
            bv[j] = *(const float4*)&Rb[(ml + 16 * j) * 64 + (k0 ^ sxb)];
        #pragma unroll
        for (int i = 0; i < 4; ++i)
            #pragma unroll
            for (int j = 0; j < 4; ++j)
                acc[i * 4 + j] += av[i].x * bv[j].x + av[i].y * bv[j].y
                                + av[i].z * bv[j].z + av[i].w * bv[j].w;
    }
}

// write full-block acc rows (acc[n][k] layout) into swizzled LDS
__device__ __forceinline__ void wr256_sw(float* M, const float* acc) {
    int nl = threadIdx.x >> 4, ml = threadIdx.x & 15;
    #pragma unroll
    for (int i = 0; i < 4; ++i)
        #pragma unroll
        for (int j = 0; j < 4; ++j) {
            int r = nl + 16 * i, k = ml + 16 * j;
            M[r * 64 + (((k & ~3) ^ ((r & 15) << 2)) | (k & 3))] = acc[i * 4 + j];
        }
}

// store 64x64 result row-major to global
__device__ __forceinline__ void store_mat(float* __restrict__ G, const float* acc) {
    int nl = threadIdx.x >> 4, ml = threadIdx.x & 15;
    #pragma unroll
    for (int i = 0; i < 4; ++i)
        #pragma unroll
        for (int j = 0; j < 4; ++j)
            G[(nl + 16 * i) * 64 + ml + 16 * j] = acc[i * 4 + j];
}

// store aa + fused loss from registers (proven epilogue)
__device__ __forceinline__ void store_loss(const float* acc, float* __restrict__ aa,
                                           float* __restrict__ out, float* red) {
    int tid = threadIdx.x;
    int nl = tid >> 4, ml = tid & 15;
    #pragma unroll
    for (int i = 0; i < 4; ++i)
        #pragma unroll
        for (int j = 0; j < 4; ++j)
            aa[(nl + 16 * i) * 64 + (ml + 16 * j)] = acc[i * 4 + j];
    int l = tid & 63;
    float part = 0.f;
    #pragma unroll
    for (int i = 0; i < 4; ++i) {
        float rsum = acc[i * 4 + 0] + acc[i * 4 + 1] + acc[i * 4 + 2] + acc[i * 4 + 3];
        rsum += __shfl_down(rsum, 8, 16);
        rsum += __shfl_down(rsum, 4, 16);
        rsum += __shfl_down(rsum, 2, 16);
        rsum += __shfl_down(rsum, 1, 16);
        float dv = __shfl(acc[5 * i], (l & 48) | nl, 64);
        if ((l & 15) == 0) part += logf(rsum + 6.4e-19f) - logf(dv + 1e-20f);
    }
    for (int off = 32; off; off >>= 1) part += __shfl_down(part, off);
    if (l == 0) red[tid >> 6] = part;
    __syncthreads();
    if (tid == 0) atomicAdd(out, (red[0] + red[1] + red[2] + red[3]) * (1.f / 128.f));
}

// device-scope spin barrier; single-use counter. Keep barrier grids TINY:
// 256-block version measured +50us (R2).
__device__ __forceinline__ void gbar(int* cnt, int target) {
    __threadfence();
    __syncthreads();
    if (threadIdx.x == 0) {
        __hip_atomic_fetch_add(cnt, 1, __ATOMIC_ACQ_REL, __HIP_MEMORY_SCOPE_AGENT);
        while (__hip_atomic_load(cnt, __ATOMIC_ACQUIRE, __HIP_MEMORY_SCOPE_AGENT) < target)
            __builtin_amdgcn_s_sleep(2);
    }
    __syncthreads();
    __threadfence();
}

// ---------------------------------------------------------------------------
// K3: fused As+zero_softmax+chain. grid = 6, block = 256, TWO device barriers.
// phase A  (6 blk): As/zero_softmax job (b,t); write only consumed layouts.
//   bar0(6); blocks 4,5 exit after arrival.
// phase B' (4 blk): blk 2b+0: P=A12_0@A12_1 (kept in LDS), L=P@A12_2 -> wsL
//                   blk 2b+1: R1T=A21_0^T@A21_1^T (LDS + wsR1T), RT=R1T@A21_2^T (LDS)
//   bar1(4)
// phase C' (4 blk): blk 2b+0: aa1_b = P @ R1 (+loss)   [P local, R1T staged]
//                   blk 2b+1: aa2_b = L @ R  (+loss)   [RT local, L staged]
__global__ void __launch_bounds__(256, 1)
k_tail(const float* __restrict__ qsp,
       float* __restrict__ a12, float* __restrict__ a12T,
       float* __restrict__ a21, float* __restrict__ a21T,
       float* __restrict__ wsR1T, float* __restrict__ wsL,
       float* __restrict__ out, int* __restrict__ bar) {
    __shared__ float SM[16384];           // 64 KB, aliased per phase
    float* M0 = SM;
    float* M1 = SM + 4096;
    float* M2 = SM + 8192;
    float* M3 = SM + 12288;
    const int tid = threadIdx.x;
    const int blk = blockIdx.x;

    // ---------------- phase A: As + zero_softmax -------------------------
    {
        int t = blk % 3, b = blk / 3;
        float4* qaT4 = (float4*)SM;              // [64][32] swizzled (s-major)
        float4* qbT4 = (float4*)SM + 2048;
        {
            // qsp is already stored swizzled: staging is a pure float4 copy.
            const float4* gA = (const float4*)(qsp + (size_t)(b * 4 + t) * 8192);
            const float4* gB = (const float4*)(qsp + (size_t)(b * 4 + t + 1) * 8192);
            #pragma unroll
            for (int it = 0; it < 8; ++it) {
                int idx = it * 256 + tid;
                qaT4[idx] = gA[idx];
                qbT4[idx] = gB[idx];
            }
        }
        __syncthreads();

        const int nl = tid >> 4, ml = tid & 15;
        float acc[16];
        #pragma unroll
        for (int i = 0; i < 16; ++i) acc[i] = 0.f;
        #pragma unroll 8
        for (int k4 = 0; k4 < 32; ++k4) {
            float4 av[4], bv[4];
            #pragma unroll
            for (int i = 0; i < 4; ++i) { int n = nl + 16 * i; av[i] = qaT4[n * 32 + (k4 ^ (n & 31))]; }
            #pragma unroll
            for (int j = 0; j < 4; ++j) { int m = ml + 16 * j; bv[j] = qbT4[m * 32 + (k4 ^ (m & 31))]; }
            #pragma unroll
            for (int i = 0; i < 4; ++i)
                #pragma unroll
                for (int j = 0; j < 4; ++j)
                    acc[i * 4 + j] += av[i].x * bv[j].x + av[i].y * bv[j].y
                                    + av[i].z * bv[j].z + av[i].w * bv[j].w;
        }
        __syncthreads();

        float* eb = (float*)qaT4;          // [64][65]
        float* rs = (float*)qbT4;          // [64]
        float* cs = rs + 64;               // [64]
        #pragma unroll
        for (int i = 0; i < 4; ++i)
            #pragma unroll
            for (int j = 0; j < 4; ++j) {
                int n = nl + 16 * i, m = ml + 16 * j;
                float x = acc[i * 4 + j] * (1.f / 0.07f);
                float e = expf(x) - 1.f;
                eb[n * 65 + m] = e * e;
            }
        __syncthreads();
        if (tid < 128) {
            int r = tid & 63; bool isrow = tid < 64;
            float a = 0.f;
            #pragma unroll
            for (int k = 0; k < 64; ++k) a += isrow ? eb[r * 65 + k] : eb[k * 65 + r];
            (isrow ? rs : cs)[r] = a + 1e-5f;
        }
        __syncthreads();
        // Only the orientations the chain consumes:
        //   t==0: A12_0 rows, A21_0^T rows;  t>0: A12_t^T rows, A21_t rows
        float* p12  = a12  + (b * 3 + t) * 4096;
        float* p12T = a12T + (b * 3 + t) * 4096;
        float* p21  = a21  + (b * 3 + t) * 4096;
        float* p21T = a21T + (b * 3 + t) * 4096;
        #pragma unroll
        for (int i = 0; i < 4; ++i)
            #pragma unroll
            for (int j = 0; j < 4; ++j) {
                int n = nl + 16 * i, m = ml + 16 * j;
                float v   = eb[n * 65 + m];
                float v12 = v / rs[n];           // A12[n][m]
                float v21 = v / cs[m];           // A21[m][n]
                if (t == 0) {
                    p12 [n * 64 + m] = v12;      // A12_0 rows
                    p21T[n * 64 + m] = v21;      // A21_0^T rows
                } else {
                    p12T[m * 64 + n] = v12;      // A12_t^T rows
                    p21 [m * 64 + n] = v21;      // A21_t rows
                }
            }
    }
    gbar(bar + 0, 6);
    if (blk >= 4) return;                 // blocks 4,5 done (arrived at bar0)

    // ---------------- phase B': 2 mms per block, intermediates stay in LDS -
    int b = blk >> 1, odd = blk & 1;
    if (!odd) {
        // P = A12_0 @ A12_1 (keep in M2); L = P @ A12_2 -> wsL
        stage2(M0, M1, a12 + (b * 3 + 0) * 4096, a12T + (b * 3 + 1) * 4096);
        __syncthreads();
        float acc[16];
        mm256_sw(acc, M0, M1);                    // P
        wr256_sw(M2, acc);                        // P rows, local
        stage1(M3, a12T + (b * 3 + 2) * 4096);    // A12_2^T rows
        __syncthreads();
        float acc2[16];
        mm256_sw(acc2, M2, M3);                   // L = P @ A12_2
        store_mat(wsL + b * 4096, acc2);          // partner needs L
    } else {
        // R1T = A21_0^T @ A21_1^T (keep in M2 + publish); RT = R1T @ A21_2^T (keep in M1)
        stage2(M0, M1, a21T + (b * 3 + 0) * 4096, a21 + (b * 3 + 1) * 4096);
        __syncthreads();
        float acc[16];
        mm256_sw(acc, M0, M1);                    // R1T
        store_mat(wsR1T + b * 4096, acc);         // partner needs R1T
        wr256_sw(M2, acc);                        // R1T rows, local
        stage1(M3, a21 + (b * 3 + 2) * 4096);     // A21_2 rows
        __syncthreads();
        float acc2[16];
        mm256_sw(acc2, M2, M3);                   // RT[n][m] = (A21_2@R1)^T
        wr256_sw(M1, acc2);                       // RT rows, local (Rb of aa2)
    }
    gbar(bar + 1, 4);

    // ---------------- phase C': final mms + fused loss ---------------------
    if (!odd) {
        // aa1_b = P @ R1 : Ra = M2 (P, resident), Rb = R1T_b staged
        stage1(M3, wsR1T + b * 4096);
        __syncthreads();
        float acc[16];
        mm256_sw(acc, M2, M3);
        store_loss(acc, out + 1 + b * 4096, out, M0);
    } else {
        // aa2_b = L @ R : Ra = L_b staged, Rb = M1 (RT, resident)
        stage1(M0, wsL + b * 4096);
        __syncthreads();
        float acc[16];
        mm256_sw(acc, M0, M1);
        store_loss(acc, out + 1 + (2 + b) * 4096, out, M2);
    }
}

// ---------------------------------------------------------------------------
extern "C" void kernel_launch(void* const* d_in, const int* in_sizes, int n_in,
                              void* d_out, int out_size, void* d_ws, size_t ws_size,
                              hipStream_t stream) {
    const float* feats = (const float*)d_in[0];
    const float* Wh    = (const float*)d_in[1];
    const int*   mask  = (const int*)d_in[2];
    float* out = (float*)d_out;
    float* ws  = (float*)d_ws;

    float* ws_sums = ws + OFF_WS;
    float* q       = ws + OFF_Q;
    float* qsp     = ws + OFF_QSP;
    float* a12     = ws + OFF_A12;
    float* a12T    = ws + OFF_A12T;
    float* a21     = ws + OFF_A21;
    float* a21T    = ws + OFF_A21T;
    float* wsR1T   = ws + OFF_R1T;
    float* wsL     = ws + OFF_L;
    int*   bar     = (int*)(ws + OFF_BAR);

    k_front<<<392 + 2 * NWIN, 256, 0, stream>>>(mask, feats, Wh, ws_sums, q);
    k_qsp<<<256, 256, 0, stream>>>(q, ws_sums, qsp, out, bar);
    k_tail<<<6, 256, 0, stream>>>(qsp, a12, a12T, a21, a21T,
                                  wsR1T, wsL, out, bar);
}